// Round 15
// baseline (185.638 us; speedup 1.0000x reference)
//
#include <hip/hip_runtime.h>

#define TPB 256
constexpr int DIN = 47;
constexpr int HID = 128;
constexpr int LAT = 64;
constexpr int GG  = 1024;
constexpr int NBMAX = 512;
constexpr int PBH = 256;     // hist/scatter edge slices
constexpr int EMBG = 512;    // embed grid

typedef __attribute__((ext_vector_type(8))) short short8v;
typedef __attribute__((ext_vector_type(4))) float float4v;

__device__ inline ushort f2bf(float f) {
  uint32_t u = __float_as_uint(f);
  return (ushort)((u + 0x7FFFu + ((u >> 16) & 1u)) >> 16);
}
__device__ inline float bf2f(ushort s) {
  return __uint_as_float(((uint32_t)s) << 16);
}

// ------- embed (MFMA) + edge histogram fused (hist only in blocks < PBH) -------
__global__ __launch_bounds__(256) void embed_hist_kernel(
    const float* __restrict__ x, const float* __restrict__ W,
    const float* __restrict__ b, ushort* __restrict__ out, int n,
    const int* __restrict__ dst, int* __restrict__ blockhist, int e, int nbuck) {
  __shared__ int hist[NBMAX];
  __shared__ ushort Wt[HID * 64];
  __shared__ float bl[HID];
  const int tid = threadIdx.x;
  const bool doHist = (blockIdx.x < PBH);
  if (doHist) {
    for (int i = tid; i < nbuck; i += TPB) hist[i] = 0;
  }
  __syncthreads();
  if (doHist) {
    const int per = (e + PBH - 1) / PBH;
    const int lo = blockIdx.x * per;
    const int hi = min(lo + per, e);
    for (int i = lo + tid; i < hi; i += TPB)
      atomicAdd(&hist[dst[i] >> 8], 1);
  }
  for (int i = tid; i < HID * 64; i += TPB) {
    int c = i & (HID - 1), k = i >> 7;
    ushort v = (k < DIN) ? f2bf(W[k * HID + c]) : (ushort)0;
    Wt[c * 64 + (k ^ ((c & 7) << 3))] = v;
  }
  if (tid < HID) bl[tid] = b[tid];
  __syncthreads();
  if (doHist) {
    for (int i = tid; i < nbuck; i += TPB)
      blockhist[(size_t)i * PBH + blockIdx.x] = hist[i];
  }
  const int lane = tid & 63, wave = tid >> 6;
  const int rowA = lane & 15, kgrp = lane >> 4;
  for (int nb0 = blockIdx.x * 64; nb0 < n; nb0 += gridDim.x * 64) {
    const int tbase = nb0 + wave * 16;
    int nodeA = tbase + rowA; if (nodeA >= n) nodeA = n - 1;
    const float* xr = x + (size_t)nodeA * DIN;
    short8v a0, a1;
    #pragma unroll
    for (int j = 0; j < 8; ++j) {
      int k0 = kgrp * 8 + j;
      a0[j] = (short)f2bf(xr[k0]);
      int k1 = 32 + kgrp * 8 + j;
      a1[j] = (short)((k1 < DIN) ? f2bf(xr[k1]) : (ushort)0);
    }
    #pragma unroll
    for (int ct = 0; ct < HID / 16; ++ct) {
      const int c = ct * 16 + rowA;
      const int sw = (c & 7) << 3;
      const ushort* wc = &Wt[c * 64];
      float4v acc = {0.f, 0.f, 0.f, 0.f};
      acc = __builtin_amdgcn_mfma_f32_16x16x32_bf16(a0, *(const short8v*)(wc + ((kgrp * 8)      ^ sw)), acc, 0, 0, 0);
      acc = __builtin_amdgcn_mfma_f32_16x16x32_bf16(a1, *(const short8v*)(wc + ((kgrp * 8 + 32) ^ sw)), acc, 0, 0, 0);
      float bc = bl[c];
      #pragma unroll
      for (int r = 0; r < 4; ++r) {
        int node = tbase + kgrp * 4 + r;
        if (node < n) out[(size_t)node * HID + c] = f2bf(fmaxf(acc[r] + bc, 0.f));
      }
    }
  }
}

// ------- lin+quant fused (MFMA): q[n,OD] int8 (PERMUTED cols) + scale + sdinv -------
template <int OD, bool PERMW>
__global__ __launch_bounds__(256) void lin_q_kernel(
    const ushort* __restrict__ h, const float* __restrict__ W,
    unsigned char* __restrict__ q, float* __restrict__ scaleq,
    float* __restrict__ sdinv, const float* __restrict__ dinv, int n) {
  constexpr int NCT = OD / 16;
  __shared__ ushort Wt[OD * 128];
  const int tid = threadIdx.x;
  for (int idx = tid; idx < 128 * OD; idx += TPB) {
    int k = idx / OD, c = idx - k * OD;
    int ks = PERMW ? (8 * (k & 15) + (k >> 4)) : k;
    Wt[c * 128 + (ks ^ ((c & 7) << 3))] = f2bf(W[idx]);
  }
  __syncthreads();
  const int lane = tid & 63, wave = tid >> 6;
  const int rowA = lane & 15, kgrp = lane >> 4;
  const int nb0 = blockIdx.x * 64 + wave * 16;
  int nodeA = nb0 + rowA; if (nodeA >= n) nodeA = n - 1;
  const ushort* hrow = h + (size_t)nodeA * 128 + kgrp * 8;
  short8v a0 = *(const short8v*)(hrow);
  short8v a1 = *(const short8v*)(hrow + 32);
  short8v a2 = *(const short8v*)(hrow + 64);
  short8v a3 = *(const short8v*)(hrow + 96);
  float accv[NCT][4];
  #pragma unroll
  for (int ct = 0; ct < NCT; ++ct) {
    const int c = ct * 16 + rowA;
    const int sw = (c & 7) << 3;
    const ushort* wc = &Wt[c * 128];
    float4v acc = {0.f, 0.f, 0.f, 0.f};
    acc = __builtin_amdgcn_mfma_f32_16x16x32_bf16(a0, *(const short8v*)(wc + ((kgrp * 8)       ^ sw)), acc, 0, 0, 0);
    acc = __builtin_amdgcn_mfma_f32_16x16x32_bf16(a1, *(const short8v*)(wc + ((kgrp * 8 + 32)  ^ sw)), acc, 0, 0, 0);
    acc = __builtin_amdgcn_mfma_f32_16x16x32_bf16(a2, *(const short8v*)(wc + ((kgrp * 8 + 64)  ^ sw)), acc, 0, 0, 0);
    acc = __builtin_amdgcn_mfma_f32_16x16x32_bf16(a3, *(const short8v*)(wc + ((kgrp * 8 + 96)  ^ sw)), acc, 0, 0, 0);
    #pragma unroll
    for (int r = 0; r < 4; ++r) accv[ct][r] = acc[r];
  }
  #pragma unroll
  for (int r = 0; r < 4; ++r) {
    float m = 0.f;
    #pragma unroll
    for (int ct = 0; ct < NCT; ++ct) m = fmaxf(m, fabsf(accv[ct][r]));
    m = fmaxf(m, __shfl_xor(m, 1));
    m = fmaxf(m, __shfl_xor(m, 2));
    m = fmaxf(m, __shfl_xor(m, 4));
    m = fmaxf(m, __shfl_xor(m, 8));
    float inv = (m > 0.f) ? 127.f / m : 0.f;
    unsigned int pk[NCT / 4];
    #pragma unroll
    for (int wq = 0; wq < NCT / 4; ++wq) {
      unsigned int p = 0;
      #pragma unroll
      for (int j = 0; j < 4; ++j) {
        int qv = (int)rintf(accv[wq * 4 + j][r] * inv) + 128;
        p |= ((unsigned int)(qv & 255)) << (8 * j);
      }
      pk[wq] = p;
    }
    int node = nb0 + kgrp * 4 + r;
    if (node < n) {
      unsigned char* qr = q + (size_t)node * OD + rowA * NCT;
      if (NCT == 8) *(uint2*)qr = make_uint2(pk[0], pk[NCT / 4 - 1]);
      else          *(unsigned int*)qr = pk[0];
      if (rowA == 0) {
        float sc = m * (1.f / 127.f);
        scaleq[node] = sc;
        sdinv[node] = sc * dinv[node];
      }
    }
  }
}

// ---------------- scans ----------------
__global__ void scanG1_kernel(int* __restrict__ a, int* __restrict__ bsum, int m) {
  __shared__ int sh[TPB];
  int i = blockIdx.x * TPB + threadIdx.x;
  int v = (i < m) ? a[i] : 0;
  sh[threadIdx.x] = v;
  __syncthreads();
  for (int off = 1; off < TPB; off <<= 1) {
    int t = (threadIdx.x >= off) ? sh[threadIdx.x - off] : 0;
    __syncthreads();
    sh[threadIdx.x] += t;
    __syncthreads();
  }
  if (i < m) a[i] = sh[threadIdx.x] - v;
  if (threadIdx.x == TPB - 1) bsum[blockIdx.x] = sh[threadIdx.x];
}

__global__ void scan2_kernel(int* __restrict__ bsum, int nb) {
  __shared__ int sh[512];
  __shared__ int carry;
  if (threadIdx.x == 0) carry = 0;
  __syncthreads();
  for (int base = 0; base < nb; base += 512) {
    int i = base + threadIdx.x;
    int v = (i < nb) ? bsum[i] : 0;
    sh[threadIdx.x] = v;
    __syncthreads();
    for (int off = 1; off < 512; off <<= 1) {
      int t = (threadIdx.x >= off) ? sh[threadIdx.x - off] : 0;
      __syncthreads();
      sh[threadIdx.x] += t;
      __syncthreads();
    }
    if (i < nb) bsum[i] = carry + sh[threadIdx.x] - v;
    __syncthreads();
    if (threadIdx.x == 0) carry += sh[511];
    __syncthreads();
  }
}

// scatter edges into bucket segments; packed uint32 (src<<8 | dst&255); gstart fused
__global__ __launch_bounds__(256) void scatterA_kernel(
    const int* __restrict__ src, const int* __restrict__ dst,
    const int* __restrict__ off, const int* __restrict__ bsum,
    unsigned int* __restrict__ ppack, int e, int nbuck,
    const int* __restrict__ batch, int* __restrict__ gstart, int n, int G) {
  __shared__ int ofs[NBMAX];
  const int tid = threadIdx.x;
  const int blk = blockIdx.x;
  for (int i = tid; i < nbuck; i += TPB)
    ofs[i] = off[(size_t)i * PBH + blk] + bsum[i];
  __syncthreads();
  const int per = (e + PBH - 1) / PBH;
  const int lo = blk * per;
  const int hi = min(lo + per, e);
  for (int i = lo + tid; i < hi; i += TPB) {
    int s = src[i], d = dst[i];
    int p = atomicAdd(&ofs[d >> 8], 1);
    ppack[p] = ((unsigned)s << 8) | ((unsigned)d & 255u);
  }
  for (int i = blk * TPB + tid; i < n; i += PBH * TPB) {
    int bi = batch[i];
    int bp = (i == 0) ? -1 : batch[i - 1];
    for (int g = bp + 1; g <= bi; ++g) gstart[g] = i;
    if (i == n - 1)
      for (int g = bi + 1; g <= G; ++g) gstart[g] = n;
  }
}

__global__ __launch_bounds__(256) void bucketB_kernel(
    const unsigned int* __restrict__ ppack, const int* __restrict__ off,
    const int* __restrict__ bsum, int* __restrict__ rowptr,
    float* __restrict__ dinv, int* __restrict__ csr_src,
    int n, int e, int nbuck) {
  __shared__ int cnt[256];
  __shared__ int sh[256];
  const int tid = threadIdx.x;
  const int b = blockIdx.x;
  const int bs = off[(size_t)b * PBH] + bsum[b];
  const int be = (b + 1 < nbuck) ? (off[(size_t)(b + 1) * PBH] + bsum[b + 1]) : e;
  cnt[tid] = 0;
  __syncthreads();
  for (int i = bs + tid; i < be; i += TPB)
    atomicAdd(&cnt[ppack[i] & 255u], 1);
  __syncthreads();
  const int deg = cnt[tid];
  sh[tid] = deg;
  __syncthreads();
  for (int o = 1; o < 256; o <<= 1) {
    int t = (tid >= o) ? sh[tid - o] : 0;
    __syncthreads();
    sh[tid] += t;
    __syncthreads();
  }
  const int loff = sh[tid] - deg;
  const int node = b * 256 + tid;
  if (node < n) {
    rowptr[node] = bs + loff;
    dinv[node] = rsqrtf((float)deg + 1.f);
  }
  if (b == nbuck - 1 && tid == TPB - 1) rowptr[n] = e;
  cnt[tid] = loff;
  __syncthreads();
  for (int i = bs + tid; i < be; i += TPB) {
    unsigned int p = ppack[i];
    int pos = atomicAdd(&cnt[p & 255u], 1);
    csr_src[bs + pos] = (int)(p >> 8);
  }
}

// --- gather int8 (permuted cols), uint4 loads: OD/16 lanes/node, 16 B/lane/edge ---
template <int OD>
__global__ __launch_bounds__(256) void gather_i8_kernel(
    const unsigned char* __restrict__ q, const float* __restrict__ scale,
    const float* __restrict__ sdinv, const int* __restrict__ rowptr,
    const int* __restrict__ csr_src, const float* __restrict__ dinv,
    const float* __restrict__ b, ushort* __restrict__ out, int n) {
  constexpr int Q4 = OD / 16;                  // lanes per node: 8 or 4
  constexpr int NS = TPB / Q4;                 // nodes per block: 32 or 64
  const int tid = threadIdx.x;
  const int tx = tid & (Q4 - 1), slot = tid / Q4;
  int node = blockIdx.x * NS + slot;
  if (node >= n) return;
  const uint4* qrow = (const uint4*)q;         // row stride = Q4 uint4
  int start = rowptr[node], end = rowptr[node + 1];
  float di = dinv[node];
  float acc[16];
  #pragma unroll
  for (int c = 0; c < 16; ++c) acc[c] = 0.f;
  float wsum = 0.f;
  int j = start;
  for (; j + 3 < end; j += 4) {
    int s[4]; uint4 v[4]; float w[4];
    #pragma unroll
    for (int u = 0; u < 4; ++u) s[u] = csr_src[j + u];
    #pragma unroll
    for (int u = 0; u < 4; ++u) v[u] = qrow[(size_t)s[u] * Q4 + tx];
    #pragma unroll
    for (int u = 0; u < 4; ++u) w[u] = sdinv[s[u]];
    #pragma unroll
    for (int u = 0; u < 4; ++u) {
      wsum += w[u];
      const unsigned int wd[4] = {v[u].x, v[u].y, v[u].z, v[u].w};
      #pragma unroll
      for (int t = 0; t < 4; ++t) {
        acc[4 * t + 0] += w[u] * (float)( wd[t]        & 255u);
        acc[4 * t + 1] += w[u] * (float)((wd[t] >>  8) & 255u);
        acc[4 * t + 2] += w[u] * (float)((wd[t] >> 16) & 255u);
        acc[4 * t + 3] += w[u] * (float)( wd[t] >> 24);
      }
    }
  }
  for (; j < end; ++j) {
    int s0 = csr_src[j];
    uint4 v0 = qrow[(size_t)s0 * Q4 + tx];
    float w0 = sdinv[s0];
    wsum += w0;
    const unsigned int wd[4] = {v0.x, v0.y, v0.z, v0.w};
    #pragma unroll
    for (int t = 0; t < 4; ++t) {
      acc[4 * t + 0] += w0 * (float)( wd[t]        & 255u);
      acc[4 * t + 1] += w0 * (float)((wd[t] >>  8) & 255u);
      acc[4 * t + 2] += w0 * (float)((wd[t] >> 16) & 255u);
      acc[4 * t + 3] += w0 * (float)( wd[t] >> 24);
    }
  }
  // self term
  uint4 sv = qrow[(size_t)node * Q4 + tx];
  float ss = scale[node] * di * di;
  float su[16];
  {
    const unsigned int wd[4] = {sv.x, sv.y, sv.z, sv.w};
    #pragma unroll
    for (int t = 0; t < 4; ++t) {
      su[4 * t + 0] = (float)( wd[t]        & 255u);
      su[4 * t + 1] = (float)((wd[t] >>  8) & 255u);
      su[4 * t + 2] = (float)((wd[t] >> 16) & 255u);
      su[4 * t + 3] = (float)( wd[t] >> 24);
    }
  }
  // bias at TRUE col of storage byte p = 16*tx + j2
  float bb[16];
  #pragma unroll
  for (int j2 = 0; j2 < 16; ++j2) {
    int ctrue = (OD == 128) ? (16 * (j2 & 7) + 2 * tx + (j2 >> 3))
                            : (16 * (j2 & 3) + 4 * tx + (j2 >> 2));
    bb[j2] = b[ctrue];
  }
  short8v o0, o1;
  #pragma unroll
  for (int c = 0; c < 16; ++c) {
    float val = di * (acc[c] - 128.f * wsum) + ss * (su[c] - 128.f) + bb[c];
    ushort ob = f2bf(fmaxf(val, 0.f));
    if (c < 8) o0[c] = (short)ob; else o1[c - 8] = (short)ob;
  }
  ushort* op = out + (size_t)node * OD + 16 * tx;
  *(short8v*)(op) = o0;
  *(short8v*)(op + 8) = o1;
}

// ---------------- pool: vectorized segment mean over pi64-permuted h2 ----------------
__global__ __launch_bounds__(256) void pool2_kernel(
    const ushort* __restrict__ h, const int* __restrict__ gstart,
    float* __restrict__ out) {
  __shared__ float sh[32][LAT];
  int g = blockIdx.x;
  int s = gstart[g], epos = gstart[g + 1];
  int grp = threadIdx.x >> 3, oct = threadIdx.x & 7;
  float acc[8];
  #pragma unroll
  for (int j = 0; j < 8; ++j) acc[j] = 0.f;
  for (int i = s + grp; i < epos; i += 32) {
    uint4 v = *(const uint4*)(h + (size_t)i * LAT + oct * 8);
    const ushort* pv = (const ushort*)&v;
    #pragma unroll
    for (int j = 0; j < 8; ++j) acc[j] += bf2f(pv[j]);
  }
  #pragma unroll
  for (int j = 0; j < 8; ++j) sh[grp][oct * 8 + j] = acc[j];
  __syncthreads();
  if (threadIdx.x < LAT) {
    int c = threadIdx.x;
    float v = 0.f;
    #pragma unroll
    for (int k = 0; k < 32; ++k) v += sh[k][c];
    int ctrue = 16 * (c & 3) + (c >> 2);        // pi64
    out[(size_t)g * LAT + ctrue] = v / fmaxf((float)(epos - s), 1.f);
  }
}

extern "C" void kernel_launch(void* const* d_in, const int* in_sizes, int n_in,
                              void* d_out, int out_size, void* d_ws, size_t ws_size,
                              hipStream_t stream) {
  const float* x     = (const float*)d_in[0];
  const float* W_emb = (const float*)d_in[1];
  const float* b_emb = (const float*)d_in[2];
  const float* W1    = (const float*)d_in[3];
  const float* b1    = (const float*)d_in[4];
  const float* W2    = (const float*)d_in[5];
  const float* b2    = (const float*)d_in[6];
  const int*   ei    = (const int*)d_in[7];
  const int*   batch = (const int*)d_in[8];
  const int n = in_sizes[8];
  const int e = in_sizes[7] / 2;
  const int* srcp = ei;
  const int* dstp = ei + e;
  float* out = (float*)d_out;

  char* ws = (char*)d_ws;
  size_t off_ = 0;
  auto alloc = [&](size_t bytes) {
    void* p = ws + off_;
    off_ += (bytes + 255) & ~(size_t)255;
    return p;
  };
  ushort* bufA    = (ushort*)alloc((size_t)n * HID * 2);
  unsigned char* bufQ = (unsigned char*)alloc((size_t)n * HID);
  float*  scaleq  = (float*)alloc((size_t)n * 4);
  float*  sdinv   = (float*)alloc((size_t)n * 4);
  float*  dinv    = (float*)alloc((size_t)n * 4);
  int*    blockhist = (int*)alloc((size_t)NBMAX * PBH * 4);
  int*    rowptr  = (int*)alloc((size_t)(n + 1) * 4);
  int*    bsum    = (int*)alloc((size_t)1024 * 4);
  unsigned int* ppack = (unsigned int*)alloc((size_t)e * 4);
  int*    csr_src = (int*)alloc((size_t)e * 4);
  int*    gstart  = (int*)alloc((size_t)(GG + 1) * 4);

  const int nbuck = (n + 255) / 256;           // 391
  const int m = nbuck * PBH;                   // scan length
  const int mb2 = (m + TPB - 1) / TPB;         // == nbuck
  const int mb = (n + 63) / 64;

  // h0 (MFMA) + edge histogram, fused
  embed_hist_kernel<<<EMBG, TPB, 0, stream>>>(x, W_emb, b_emb, bufA, n,
                                              dstp, blockhist, e, nbuck);

  // scan; scatter (packed uint32); per-bucket sort
  scanG1_kernel<<<mb2, TPB, 0, stream>>>(blockhist, bsum, m);
  scan2_kernel<<<1, 512, 0, stream>>>(bsum, mb2);
  scatterA_kernel<<<PBH, TPB, 0, stream>>>(srcp, dstp, blockhist, bsum, ppack, e, nbuck,
                                           batch, gstart, n, GG);
  bucketB_kernel<<<nbuck, TPB, 0, stream>>>(ppack, blockhist, bsum, rowptr, dinv,
                                            csr_src, n, e, nbuck);

  // conv1
  lin_q_kernel<HID, false><<<mb, TPB, 0, stream>>>(bufA, W1, bufQ, scaleq, sdinv, dinv, n);
  gather_i8_kernel<HID><<<(n * (HID / 16) + TPB - 1) / TPB, TPB, 0, stream>>>(
      bufQ, scaleq, sdinv, rowptr, csr_src, dinv, b1, bufA, n);

  // conv2
  lin_q_kernel<LAT, true><<<mb, TPB, 0, stream>>>(bufA, W2, bufQ, scaleq, sdinv, dinv, n);
  gather_i8_kernel<LAT><<<(n * (LAT / 16) + TPB - 1) / TPB, TPB, 0, stream>>>(
      bufQ, scaleq, sdinv, rowptr, csr_src, dinv, b2, bufA, n);

  // pool (vectorized; unpermutes pi64 on final write)
  pool2_kernel<<<GG, TPB, 0, stream>>>(bufA, gstart, out);
}

// Round 16
// 173.047 us; speedup vs baseline: 1.0728x; 1.0728x over previous
//
#include <hip/hip_runtime.h>

#define TPB 256
constexpr int DIN = 47;
constexpr int HID = 128;
constexpr int LAT = 64;
constexpr int GG  = 1024;
constexpr int NBMAX = 512;
constexpr int PBH = 256;     // hist/scatter edge slices
constexpr int EMBG = 512;    // embed grid

typedef __attribute__((ext_vector_type(8))) short short8v;
typedef __attribute__((ext_vector_type(4))) float float4v;

__device__ inline ushort f2bf(float f) {
  uint32_t u = __float_as_uint(f);
  return (ushort)((u + 0x7FFFu + ((u >> 16) & 1u)) >> 16);
}
__device__ inline float bf2f(ushort s) {
  return __uint_as_float(((uint32_t)s) << 16);
}

// ------- embed (MFMA) + edge histogram fused (hist only in blocks < PBH) -------
__global__ __launch_bounds__(256) void embed_hist_kernel(
    const float* __restrict__ x, const float* __restrict__ W,
    const float* __restrict__ b, ushort* __restrict__ out, int n,
    const int* __restrict__ dst, int* __restrict__ blockhist, int e, int nbuck) {
  __shared__ int hist[NBMAX];
  __shared__ ushort Wt[HID * 64];
  __shared__ float bl[HID];
  const int tid = threadIdx.x;
  const bool doHist = (blockIdx.x < PBH);
  if (doHist) {
    for (int i = tid; i < nbuck; i += TPB) hist[i] = 0;
  }
  __syncthreads();
  if (doHist) {
    const int per = (e + PBH - 1) / PBH;
    const int lo = blockIdx.x * per;
    const int hi = min(lo + per, e);
    for (int i = lo + tid; i < hi; i += TPB)
      atomicAdd(&hist[dst[i] >> 8], 1);
  }
  for (int i = tid; i < HID * 64; i += TPB) {
    int c = i & (HID - 1), k = i >> 7;
    ushort v = (k < DIN) ? f2bf(W[k * HID + c]) : (ushort)0;
    Wt[c * 64 + (k ^ ((c & 7) << 3))] = v;
  }
  if (tid < HID) bl[tid] = b[tid];
  __syncthreads();
  if (doHist) {
    for (int i = tid; i < nbuck; i += TPB)
      blockhist[(size_t)i * PBH + blockIdx.x] = hist[i];
  }
  const int lane = tid & 63, wave = tid >> 6;
  const int rowA = lane & 15, kgrp = lane >> 4;
  for (int nb0 = blockIdx.x * 64; nb0 < n; nb0 += gridDim.x * 64) {
    const int tbase = nb0 + wave * 16;
    int nodeA = tbase + rowA; if (nodeA >= n) nodeA = n - 1;
    const float* xr = x + (size_t)nodeA * DIN;
    short8v a0, a1;
    #pragma unroll
    for (int j = 0; j < 8; ++j) {
      int k0 = kgrp * 8 + j;
      a0[j] = (short)f2bf(xr[k0]);
      int k1 = 32 + kgrp * 8 + j;
      a1[j] = (short)((k1 < DIN) ? f2bf(xr[k1]) : (ushort)0);
    }
    #pragma unroll
    for (int ct = 0; ct < HID / 16; ++ct) {
      const int c = ct * 16 + rowA;
      const int sw = (c & 7) << 3;
      const ushort* wc = &Wt[c * 64];
      float4v acc = {0.f, 0.f, 0.f, 0.f};
      acc = __builtin_amdgcn_mfma_f32_16x16x32_bf16(a0, *(const short8v*)(wc + ((kgrp * 8)      ^ sw)), acc, 0, 0, 0);
      acc = __builtin_amdgcn_mfma_f32_16x16x32_bf16(a1, *(const short8v*)(wc + ((kgrp * 8 + 32) ^ sw)), acc, 0, 0, 0);
      float bc = bl[c];
      #pragma unroll
      for (int r = 0; r < 4; ++r) {
        int node = tbase + kgrp * 4 + r;
        if (node < n) out[(size_t)node * HID + c] = f2bf(fmaxf(acc[r] + bc, 0.f));
      }
    }
  }
}

// ------- lin+quant fused (MFMA): q[n,OD] int8 (PERMUTED cols) + scale + sdinv -------
template <int OD, bool PERMW>
__global__ __launch_bounds__(256) void lin_q_kernel(
    const ushort* __restrict__ h, const float* __restrict__ W,
    unsigned char* __restrict__ q, float* __restrict__ scaleq,
    float* __restrict__ sdinv, const float* __restrict__ dinv, int n) {
  constexpr int NCT = OD / 16;
  __shared__ ushort Wt[OD * 128];
  const int tid = threadIdx.x;
  for (int idx = tid; idx < 128 * OD; idx += TPB) {
    int k = idx / OD, c = idx - k * OD;
    int ks = PERMW ? (8 * (k & 15) + (k >> 4)) : k;
    Wt[c * 128 + (ks ^ ((c & 7) << 3))] = f2bf(W[idx]);
  }
  __syncthreads();
  const int lane = tid & 63, wave = tid >> 6;
  const int rowA = lane & 15, kgrp = lane >> 4;
  const int nb0 = blockIdx.x * 64 + wave * 16;
  int nodeA = nb0 + rowA; if (nodeA >= n) nodeA = n - 1;
  const ushort* hrow = h + (size_t)nodeA * 128 + kgrp * 8;
  short8v a0 = *(const short8v*)(hrow);
  short8v a1 = *(const short8v*)(hrow + 32);
  short8v a2 = *(const short8v*)(hrow + 64);
  short8v a3 = *(const short8v*)(hrow + 96);
  float accv[NCT][4];
  #pragma unroll
  for (int ct = 0; ct < NCT; ++ct) {
    const int c = ct * 16 + rowA;
    const int sw = (c & 7) << 3;
    const ushort* wc = &Wt[c * 128];
    float4v acc = {0.f, 0.f, 0.f, 0.f};
    acc = __builtin_amdgcn_mfma_f32_16x16x32_bf16(a0, *(const short8v*)(wc + ((kgrp * 8)       ^ sw)), acc, 0, 0, 0);
    acc = __builtin_amdgcn_mfma_f32_16x16x32_bf16(a1, *(const short8v*)(wc + ((kgrp * 8 + 32)  ^ sw)), acc, 0, 0, 0);
    acc = __builtin_amdgcn_mfma_f32_16x16x32_bf16(a2, *(const short8v*)(wc + ((kgrp * 8 + 64)  ^ sw)), acc, 0, 0, 0);
    acc = __builtin_amdgcn_mfma_f32_16x16x32_bf16(a3, *(const short8v*)(wc + ((kgrp * 8 + 96)  ^ sw)), acc, 0, 0, 0);
    #pragma unroll
    for (int r = 0; r < 4; ++r) accv[ct][r] = acc[r];
  }
  #pragma unroll
  for (int r = 0; r < 4; ++r) {
    float m = 0.f;
    #pragma unroll
    for (int ct = 0; ct < NCT; ++ct) m = fmaxf(m, fabsf(accv[ct][r]));
    m = fmaxf(m, __shfl_xor(m, 1));
    m = fmaxf(m, __shfl_xor(m, 2));
    m = fmaxf(m, __shfl_xor(m, 4));
    m = fmaxf(m, __shfl_xor(m, 8));
    float inv = (m > 0.f) ? 127.f / m : 0.f;
    unsigned int pk[NCT / 4];
    #pragma unroll
    for (int wq = 0; wq < NCT / 4; ++wq) {
      unsigned int p = 0;
      #pragma unroll
      for (int j = 0; j < 4; ++j) {
        int qv = (int)rintf(accv[wq * 4 + j][r] * inv) + 128;
        p |= ((unsigned int)(qv & 255)) << (8 * j);
      }
      pk[wq] = p;
    }
    int node = nb0 + kgrp * 4 + r;
    if (node < n) {
      unsigned char* qr = q + (size_t)node * OD + rowA * NCT;
      if (NCT == 8) *(uint2*)qr = make_uint2(pk[0], pk[NCT / 4 - 1]);
      else          *(unsigned int*)qr = pk[0];
      if (rowA == 0) {
        float sc = m * (1.f / 127.f);
        scaleq[node] = sc;
        sdinv[node] = sc * dinv[node];
      }
    }
  }
}

// ---------------- scans ----------------
__global__ void scanG1_kernel(int* __restrict__ a, int* __restrict__ bsum, int m) {
  __shared__ int sh[TPB];
  int i = blockIdx.x * TPB + threadIdx.x;
  int v = (i < m) ? a[i] : 0;
  sh[threadIdx.x] = v;
  __syncthreads();
  for (int off = 1; off < TPB; off <<= 1) {
    int t = (threadIdx.x >= off) ? sh[threadIdx.x - off] : 0;
    __syncthreads();
    sh[threadIdx.x] += t;
    __syncthreads();
  }
  if (i < m) a[i] = sh[threadIdx.x] - v;
  if (threadIdx.x == TPB - 1) bsum[blockIdx.x] = sh[threadIdx.x];
}

__global__ void scan2_kernel(int* __restrict__ bsum, int nb) {
  __shared__ int sh[512];
  __shared__ int carry;
  if (threadIdx.x == 0) carry = 0;
  __syncthreads();
  for (int base = 0; base < nb; base += 512) {
    int i = base + threadIdx.x;
    int v = (i < nb) ? bsum[i] : 0;
    sh[threadIdx.x] = v;
    __syncthreads();
    for (int off = 1; off < 512; off <<= 1) {
      int t = (threadIdx.x >= off) ? sh[threadIdx.x - off] : 0;
      __syncthreads();
      sh[threadIdx.x] += t;
      __syncthreads();
    }
    if (i < nb) bsum[i] = carry + sh[threadIdx.x] - v;
    __syncthreads();
    if (threadIdx.x == 0) carry += sh[511];
    __syncthreads();
  }
}

// scatter edges into bucket segments; packed uint32 (src<<8 | dst&255); gstart fused
__global__ __launch_bounds__(256) void scatterA_kernel(
    const int* __restrict__ src, const int* __restrict__ dst,
    const int* __restrict__ off, const int* __restrict__ bsum,
    unsigned int* __restrict__ ppack, int e, int nbuck,
    const int* __restrict__ batch, int* __restrict__ gstart, int n, int G) {
  __shared__ int ofs[NBMAX];
  const int tid = threadIdx.x;
  const int blk = blockIdx.x;
  for (int i = tid; i < nbuck; i += TPB)
    ofs[i] = off[(size_t)i * PBH + blk] + bsum[i];
  __syncthreads();
  const int per = (e + PBH - 1) / PBH;
  const int lo = blk * per;
  const int hi = min(lo + per, e);
  for (int i = lo + tid; i < hi; i += TPB) {
    int s = src[i], d = dst[i];
    int p = atomicAdd(&ofs[d >> 8], 1);
    ppack[p] = ((unsigned)s << 8) | ((unsigned)d & 255u);
  }
  for (int i = blk * TPB + tid; i < n; i += PBH * TPB) {
    int bi = batch[i];
    int bp = (i == 0) ? -1 : batch[i - 1];
    for (int g = bp + 1; g <= bi; ++g) gstart[g] = i;
    if (i == n - 1)
      for (int g = bi + 1; g <= G; ++g) gstart[g] = n;
  }
}

__global__ __launch_bounds__(256) void bucketB_kernel(
    const unsigned int* __restrict__ ppack, const int* __restrict__ off,
    const int* __restrict__ bsum, int* __restrict__ rowptr,
    float* __restrict__ dinv, int* __restrict__ csr_src,
    int n, int e, int nbuck) {
  __shared__ int cnt[256];
  __shared__ int sh[256];
  const int tid = threadIdx.x;
  const int b = blockIdx.x;
  const int bs = off[(size_t)b * PBH] + bsum[b];
  const int be = (b + 1 < nbuck) ? (off[(size_t)(b + 1) * PBH] + bsum[b + 1]) : e;
  cnt[tid] = 0;
  __syncthreads();
  for (int i = bs + tid; i < be; i += TPB)
    atomicAdd(&cnt[ppack[i] & 255u], 1);
  __syncthreads();
  const int deg = cnt[tid];
  sh[tid] = deg;
  __syncthreads();
  for (int o = 1; o < 256; o <<= 1) {
    int t = (tid >= o) ? sh[tid - o] : 0;
    __syncthreads();
    sh[tid] += t;
    __syncthreads();
  }
  const int loff = sh[tid] - deg;
  const int node = b * 256 + tid;
  if (node < n) {
    rowptr[node] = bs + loff;
    dinv[node] = rsqrtf((float)deg + 1.f);
  }
  if (b == nbuck - 1 && tid == TPB - 1) rowptr[n] = e;
  cnt[tid] = loff;
  __syncthreads();
  for (int i = bs + tid; i < be; i += TPB) {
    unsigned int p = ppack[i];
    int pos = atomicAdd(&cnt[p & 255u], 1);
    csr_src[bs + pos] = (int)(p >> 8);
  }
}

// --- gather int8 (permuted col storage), uint2 loads (R14-proven shape) ---
template <int OD>
__global__ __launch_bounds__(256) void gather_i8_kernel(
    const unsigned char* __restrict__ q, const float* __restrict__ scale,
    const float* __restrict__ sdinv, const int* __restrict__ rowptr,
    const int* __restrict__ csr_src, const float* __restrict__ dinv,
    const float* __restrict__ b, ushort* __restrict__ out, int n) {
  constexpr int Q8 = OD / 8;
  constexpr int NS = TPB / Q8;
  const int tid = threadIdx.x;
  const int tx = tid & (Q8 - 1), slot = tid / Q8;
  int node = blockIdx.x * NS + slot;
  if (node >= n) return;
  const uint2* qrow = (const uint2*)q;
  int start = rowptr[node], end = rowptr[node + 1];
  float di = dinv[node];
  float acc[8];
  #pragma unroll
  for (int c = 0; c < 8; ++c) acc[c] = 0.f;
  float wsum = 0.f;
  int j = start;
  for (; j + 3 < end; j += 4) {
    int s[4]; uint2 v[4]; float w[4];
    #pragma unroll
    for (int u = 0; u < 4; ++u) s[u] = csr_src[j + u];
    #pragma unroll
    for (int u = 0; u < 4; ++u) v[u] = qrow[(size_t)s[u] * Q8 + tx];
    #pragma unroll
    for (int u = 0; u < 4; ++u) w[u] = sdinv[s[u]];
    #pragma unroll
    for (int u = 0; u < 4; ++u) {
      wsum += w[u];
      acc[0] += w[u] * (float)( v[u].x        & 255u);
      acc[1] += w[u] * (float)((v[u].x >>  8) & 255u);
      acc[2] += w[u] * (float)((v[u].x >> 16) & 255u);
      acc[3] += w[u] * (float)( v[u].x >> 24);
      acc[4] += w[u] * (float)( v[u].y        & 255u);
      acc[5] += w[u] * (float)((v[u].y >>  8) & 255u);
      acc[6] += w[u] * (float)((v[u].y >> 16) & 255u);
      acc[7] += w[u] * (float)( v[u].y >> 24);
    }
  }
  for (; j < end; ++j) {
    int s0 = csr_src[j];
    uint2 v0 = qrow[(size_t)s0 * Q8 + tx];
    float w0 = sdinv[s0];
    wsum += w0;
    acc[0] += w0 * (float)( v0.x        & 255u);
    acc[1] += w0 * (float)((v0.x >>  8) & 255u);
    acc[2] += w0 * (float)((v0.x >> 16) & 255u);
    acc[3] += w0 * (float)( v0.x >> 24);
    acc[4] += w0 * (float)( v0.y        & 255u);
    acc[5] += w0 * (float)((v0.y >>  8) & 255u);
    acc[6] += w0 * (float)((v0.y >> 16) & 255u);
    acc[7] += w0 * (float)( v0.y >> 24);
  }
  uint2 sv = qrow[(size_t)node * Q8 + tx];
  float ss = scale[node] * di * di;
  float su[8];
  su[0] = (float)( sv.x        & 255u); su[1] = (float)((sv.x >>  8) & 255u);
  su[2] = (float)((sv.x >> 16) & 255u); su[3] = (float)( sv.x >> 24);
  su[4] = (float)( sv.y        & 255u); su[5] = (float)((sv.y >>  8) & 255u);
  su[6] = (float)((sv.y >> 16) & 255u); su[7] = (float)( sv.y >> 24);
  float bb[8];
  #pragma unroll
  for (int j2 = 0; j2 < 8; ++j2) {
    int ctrue = (OD == 128) ? (16 * j2 + tx)
                            : (16 * (j2 & 3) + 2 * tx + (j2 >> 2));
    bb[j2] = b[ctrue];
  }
  short8v o;
  #pragma unroll
  for (int c = 0; c < 8; ++c) {
    float val = di * (acc[c] - 128.f * wsum) + ss * (su[c] - 128.f) + bb[c];
    o[c] = (short)f2bf(fmaxf(val, 0.f));
  }
  *(short8v*)(out + (size_t)node * OD + 8 * tx) = o;
}

// ---------------- pool: vectorized segment mean over pi64-permuted h2 ----------------
__global__ __launch_bounds__(256) void pool2_kernel(
    const ushort* __restrict__ h, const int* __restrict__ gstart,
    float* __restrict__ out) {
  __shared__ float sh[32][LAT];
  int g = blockIdx.x;
  int s = gstart[g], epos = gstart[g + 1];
  int grp = threadIdx.x >> 3, oct = threadIdx.x & 7;
  float acc[8];
  #pragma unroll
  for (int j = 0; j < 8; ++j) acc[j] = 0.f;
  for (int i = s + grp; i < epos; i += 32) {
    uint4 v = *(const uint4*)(h + (size_t)i * LAT + oct * 8);
    const ushort* pv = (const ushort*)&v;
    #pragma unroll
    for (int j = 0; j < 8; ++j) acc[j] += bf2f(pv[j]);
  }
  #pragma unroll
  for (int j = 0; j < 8; ++j) sh[grp][oct * 8 + j] = acc[j];
  __syncthreads();
  if (threadIdx.x < LAT) {
    int c = threadIdx.x;
    float v = 0.f;
    #pragma unroll
    for (int k = 0; k < 32; ++k) v += sh[k][c];
    int ctrue = 16 * (c & 3) + (c >> 2);        // pi64
    out[(size_t)g * LAT + ctrue] = v / fmaxf((float)(epos - s), 1.f);
  }
}

extern "C" void kernel_launch(void* const* d_in, const int* in_sizes, int n_in,
                              void* d_out, int out_size, void* d_ws, size_t ws_size,
                              hipStream_t stream) {
  const float* x     = (const float*)d_in[0];
  const float* W_emb = (const float*)d_in[1];
  const float* b_emb = (const float*)d_in[2];
  const float* W1    = (const float*)d_in[3];
  const float* b1    = (const float*)d_in[4];
  const float* W2    = (const float*)d_in[5];
  const float* b2    = (const float*)d_in[6];
  const int*   ei    = (const int*)d_in[7];
  const int*   batch = (const int*)d_in[8];
  const int n = in_sizes[8];
  const int e = in_sizes[7] / 2;
  const int* srcp = ei;
  const int* dstp = ei + e;
  float* out = (float*)d_out;

  char* ws = (char*)d_ws;
  size_t off_ = 0;
  auto alloc = [&](size_t bytes) {
    void* p = ws + off_;
    off_ += (bytes + 255) & ~(size_t)255;
    return p;
  };
  ushort* bufA    = (ushort*)alloc((size_t)n * HID * 2);
  unsigned char* bufQ = (unsigned char*)alloc((size_t)n * HID);
  float*  scaleq  = (float*)alloc((size_t)n * 4);
  float*  sdinv   = (float*)alloc((size_t)n * 4);
  float*  dinv    = (float*)alloc((size_t)n * 4);
  int*    blockhist = (int*)alloc((size_t)NBMAX * PBH * 4);
  int*    rowptr  = (int*)alloc((size_t)(n + 1) * 4);
  int*    bsum    = (int*)alloc((size_t)1024 * 4);
  unsigned int* ppack = (unsigned int*)alloc((size_t)e * 4);
  int*    csr_src = (int*)alloc((size_t)e * 4);
  int*    gstart  = (int*)alloc((size_t)(GG + 1) * 4);

  const int nbuck = (n + 255) / 256;           // 391
  const int m = nbuck * PBH;                   // scan length
  const int mb2 = (m + TPB - 1) / TPB;         // == nbuck
  const int mb = (n + 63) / 64;

  // h0 (MFMA) + edge histogram, fused
  embed_hist_kernel<<<EMBG, TPB, 0, stream>>>(x, W_emb, b_emb, bufA, n,
                                              dstp, blockhist, e, nbuck);

  // scan; scatter (packed uint32); per-bucket sort
  scanG1_kernel<<<mb2, TPB, 0, stream>>>(blockhist, bsum, m);
  scan2_kernel<<<1, 512, 0, stream>>>(bsum, mb2);
  scatterA_kernel<<<PBH, TPB, 0, stream>>>(srcp, dstp, blockhist, bsum, ppack, e, nbuck,
                                           batch, gstart, n, GG);
  bucketB_kernel<<<nbuck, TPB, 0, stream>>>(ppack, blockhist, bsum, rowptr, dinv,
                                            csr_src, n, e, nbuck);

  // conv1
  lin_q_kernel<HID, false><<<mb, TPB, 0, stream>>>(bufA, W1, bufQ, scaleq, sdinv, dinv, n);
  gather_i8_kernel<HID><<<(n * (HID / 8) + TPB - 1) / TPB, TPB, 0, stream>>>(
      bufQ, scaleq, sdinv, rowptr, csr_src, dinv, b1, bufA, n);

  // conv2
  lin_q_kernel<LAT, true><<<mb, TPB, 0, stream>>>(bufA, W2, bufQ, scaleq, sdinv, dinv, n);
  gather_i8_kernel<LAT><<<(n * (LAT / 8) + TPB - 1) / TPB, TPB, 0, stream>>>(
      bufQ, scaleq, sdinv, rowptr, csr_src, dinv, b2, bufA, n);

  // pool (vectorized; unpermutes pi64 on final write)
  pool2_kernel<<<GG, TPB, 0, stream>>>(bufA, gstart, out);
}